// Round 9
// baseline (406.647 us; speedup 1.0000x reference)
//
#include <hip/hip_runtime.h>

typedef _Float16 half8 __attribute__((ext_vector_type(8)));
typedef float floatx4 __attribute__((ext_vector_type(4)));

__device__ __forceinline__ float rcpf_(float x) { return __builtin_amdgcn_rcpf(x); }
__device__ __forceinline__ float exp2f_(float x) { return __builtin_amdgcn_exp2f(x); }

// Barrier that does NOT drain vmem: only LDS ops published.
// 0xC07F = vmcnt(63) expcnt(7) lgkmcnt(0).
template<bool MULTI_WAVE>
__device__ __forceinline__ void lds_publish_barrier() {
    asm volatile("" ::: "memory");
    __builtin_amdgcn_s_waitcnt(0xC07F);
    if constexpr (MULTI_WAVE) __builtin_amdgcn_s_barrier();
    asm volatile("" ::: "memory");
}

// ---------- pack Wk weights + bias into per-(dir,wave,lane) MFMA B-fragments.
// exp2-folding: gates i,f,o scaled by log2e; gate g (tanh) by 2*log2e.
template<int F_REAL, int XT, int U>
__device__ __forceinline__ void pack_one(int dir, int wave, int lane,
    const float* Wk_f, const float* b_f, const float* Wk_b, const float* b_b,
    half8* wf, float4* bf4)
{
    constexpr int N  = 4 * U;
    constexpr int NW = U / 16;
    const int quad = lane >> 4, l16 = lane & 15;
    const float* Wk = dir ? Wk_b : Wk_f;
    const float* bs = dir ? b_b  : b_f;
    const int ucol = wave * 16 + l16;
    const long base = ((long)(dir * NW + wave) * 64 + lane) * (4 * XT);
    #pragma unroll
    for (int g = 0; g < 4; g++) {
        const float sc = (g == 2) ? 2.88539008177793f : 1.44269504088896f;
        const int n = g * U + ucol;
        #pragma unroll
        for (int kt = 0; kt < XT; kt++) {
            half8 h;
            #pragma unroll
            for (int j = 0; j < 8; j++) {
                const int k = kt * 32 + quad * 8 + j;
                h[j] = (k < F_REAL) ? (_Float16)(Wk[k * N + n] * sc) : (_Float16)0;
            }
            wf[base + g * XT + kt] = h;
        }
    }
    float4 b;
    b.x = bs[0 * U + ucol] * 1.44269504088896f;
    b.y = bs[1 * U + ucol] * 1.44269504088896f;
    b.z = bs[2 * U + ucol] * 2.88539008177793f;
    b.w = bs[3 * U + ucol] * 1.44269504088896f;
    bf4[(dir * NW + wave) * 64 + lane] = b;
}

// ---------- prep: weight pack ONLY (x16 intermediate eliminated in R9).
__global__ __launch_bounds__(256)
void prep(const float* w1f_k, const float* w1f_b, const float* w1b_k, const float* w1b_b,
          const float* w2f_k, const float* w2f_b, const float* w2b_k, const float* w2b_b,
          const float* w3f_k, const float* w3f_b, const float* w3b_k, const float* w3b_b,
          half8* wf, float4* bf4)
{
    const int gid = blockIdx.x * 256 + threadIdx.x;    // 1024 threads
    if (gid < 512) {
        pack_one<78, 3, 64>(gid >> 8, (gid >> 6) & 3, gid & 63,
                            w1f_k, w1f_b, w1b_k, w1b_b, wf, bf4);
    } else if (gid < 768) {
        const int t2 = gid - 512;
        pack_one<128, 4, 32>(t2 >> 7, (t2 >> 6) & 1, t2 & 63,
                             w2f_k, w2f_b, w2b_k, w2b_b, wf + 6144, bf4 + 512);
    } else if (gid < 896) {
        const int t3 = gid - 768;
        pack_one<64, 2, 16>(t3 >> 6, 0, t3 & 63,
                            w3f_k, w3f_b, w3b_k, w3b_b, wf + 10240, bf4 + 768);
    }
}

// ---------- fused recurrence: z = in@Wk (MFMA, pre-barrier, latency hidden)
// then += h@Wr (post-barrier), exp2 gates, bias as MFMA C-init, PF-deep
// register prefetch. A rows 8..15 duplicate rows 0..7 -> NO shuffles.
// XF32: read f32 input directly (masked float2 pairs, inline cvt -- identical
// RNE rounding to the old prep conversion). No-refill epilogue: the last PF
// steps issue no loads, so no pointer ever leaves its buffer (no OOB).
template<int U, int XT, int HT, bool SEQ_OUT, int IN_F, int PF, bool XF32>
__global__ __launch_bounds__(64 * (U / 16))
void lstm_rec_fused(const void* __restrict__ in,   // [row][T][IN_F] f16 or f32
                    const half8* __restrict__ wf, const float4* __restrict__ bf4,
                    const float* __restrict__ Wr_f, const float* __restrict__ Wr_b,
                    _Float16* __restrict__ hseq, float* __restrict__ hlast)
{
    constexpr int T    = 128;
    constexpr int N    = 4 * U;
    constexpr int NW   = U / 16;
    constexpr int HROW = HT * 32 + 8;        // f16/row, 16B-aligned stride
    constexpr int THREADS = NW * 64;
    static_assert(T % PF == 0, "PF must divide T");

    const int tid  = threadIdx.x;
    const int wave = tid >> 6;
    const int lane = tid & 63;
    const int quad = lane >> 4;
    const int l16  = lane & 15;

    const int dir   = blockIdx.x >> 7;
    const int bg    = blockIdx.x & 127;
    const int bbase = bg * 8;
    const int ucol  = wave * 16 + l16;

    const float* Wr = dir ? Wr_b : Wr_f;

    __shared__ __align__(16) _Float16 H[2][8][HROW];
    for (int i = tid; i < 2 * 8 * HROW; i += THREADS)
        (&H[0][0][0])[i] = (_Float16)0;      // h0=0; pad and k>=U stay 0

    // packed Wk fragments (contiguous vector loads) + scaled bias
    const long wbase = ((long)(dir * NW + wave) * 64 + lane) * (4 * XT);
    half8 wk[4][XT];
    #pragma unroll
    for (int g = 0; g < 4; g++)
        #pragma unroll
        for (int kt = 0; kt < XT; kt++)
            wk[g][kt] = wf[wbase + g * XT + kt];
    const float4 b4 = bf4[(dir * NW + wave) * 64 + lane];
    // bias as MFMA C-init vectors (built once; removes 8 serial adds/step)
    floatx4 biasv[4];
    {
        const float bb[4] = {b4.x, b4.y, b4.z, b4.w};
        #pragma unroll
        for (int g = 0; g < 4; g++) {
            floatx4 v = {bb[g], bb[g], bb[g], bb[g]};
            biasv[g] = v;
        }
    }

    // Wr fragments, exp2-scaled at build
    half8 br[4][HT];
    #pragma unroll
    for (int g = 0; g < 4; g++) {
        const float sc = (g == 2) ? 2.88539008177793f : 1.44269504088896f;
        const int n = g * U + ucol;
        #pragma unroll
        for (int ht = 0; ht < HT; ht++) {
            half8 h;
            #pragma unroll
            for (int j = 0; j < 8; j++) {
                const int k = ht * 32 + quad * 8 + j;
                h[j] = (k < U) ? (_Float16)(Wr[k * N + n] * sc) : (_Float16)0;
            }
            br[g][ht] = h;
        }
    }

    // running per-lane input pointers (one path DCE'd); no overshoot: the
    // epilogue issues no loads, so every access stays in [0, T) rows.
    const int arow = bbase + (l16 & 7);
    const _Float16* xp  = (const _Float16*)in + (long)arow * T * IN_F + quad * 8
                        + (dir ? (long)(T - 1) * IN_F : 0);
    const float*    xpf = (const float*)in + (long)arow * T * IN_F + quad * 8
                        + (dir ? (long)(T - 1) * IN_F : 0);
    const long xd = dir ? -(long)IN_F : (long)IN_F;
    auto load_x = [&](half8* xr) {
        if constexpr (XF32) {
            #pragma unroll
            for (int kt = 0; kt < XT; kt++) {
                half8 h;
                #pragma unroll
                for (int j = 0; j < 8; j += 2) {
                    // col = kt*32 + quad*8 + j, even -> full pair iff col < 78
                    float2 v; v.x = 0.0f; v.y = 0.0f;
                    if (kt * 32 + quad * 8 + j < IN_F)
                        v = *(const float2*)(xpf + kt * 32 + j);
                    h[j]     = (_Float16)v.x;
                    h[j + 1] = (_Float16)v.y;
                }
                xr[kt] = h;
            }
            xpf += xd;
        } else {
            #pragma unroll
            for (int kt = 0; kt < XT; kt++)
                xr[kt] = *(const half8*)(xp + kt * 32);
            xp += xd;
        }
    };

    // quad -> 2 chains: q0:{0,1} q1:{4,5} q2:{2,3} q3:{6,7}
    const int rowbase = (quad & 1) * 4 + (quad >> 1) * 2;
    const bool hi_rows = (quad & 2) != 0;
    float c_reg[2] = {0.0f, 0.0f};

    const int tp0 = dir ? (T - 1) : 0;
    const long hs_stride = (long)T * (2 * U);
    _Float16* hs_ptr = SEQ_OUT
        ? hseq + ((long)(bbase + rowbase) * T + tp0) * (2 * U) + dir * U + ucol
        : nullptr;
    const long hs_delta = dir ? -(long)(2 * U) : (long)(2 * U);

    auto step = [&](int t, half8* xr, bool refill) {
        // z-part: independent of H -> issued before barrier, latency hidden
        floatx4 acc[4];
        #pragma unroll
        for (int g = 0; g < 4; g++)
            acc[g] = __builtin_amdgcn_mfma_f32_16x16x32_f16(xr[0], wk[g][0], biasv[g], 0, 0, 0);
        #pragma unroll
        for (int kt = 1; kt < XT; kt++)
            #pragma unroll
            for (int g = 0; g < 4; g++)
                acc[g] = __builtin_amdgcn_mfma_f32_16x16x32_f16(xr[kt], wk[g][kt], acc[g], 0, 0, 0);
        if (refill) load_x(xr);        // reads t+PF; stays in flight (constant-folded)
        lds_publish_barrier<(NW > 1)>();
        const _Float16* hb = &H[t & 1][l16 & 7][0];   // rows 8..15 = dup of 0..7
        #pragma unroll
        for (int ht = 0; ht < HT; ht++) {
            const half8 ha = *(const half8*)(hb + ht * 32 + quad * 8);
            #pragma unroll
            for (int g = 0; g < 4; g++)
                acc[g] = __builtin_amdgcn_mfma_f32_16x16x32_f16(ha, br[g][ht], acc[g], 0, 0, 0);
        }
        float hq[2];
        #pragma unroll
        for (int s = 0; s < 2; s++) {
            const int r = hi_rows ? (2 + s) : s;
            const float ig = rcpf_(1.0f + exp2f_(-acc[0][r]));
            const float fg = rcpf_(1.0f + exp2f_(-acc[1][r]));
            const float gg = 1.0f - 2.0f * rcpf_(exp2f_(acc[2][r]) + 1.0f);
            const float og = rcpf_(1.0f + exp2f_(-acc[3][r]));
            const float c  = fg * c_reg[s] + ig * gg;
            c_reg[s] = c;
            const float th = 1.0f - 2.0f * rcpf_(exp2f_(c * 2.88539008177793f) + 1.0f);
            hq[s] = og * th;
        }
        #pragma unroll
        for (int s = 0; s < 2; s++)
            H[(t + 1) & 1][rowbase + s][ucol] = (_Float16)hq[s];
        if constexpr (SEQ_OUT) {
            #pragma unroll
            for (int s = 0; s < 2; s++)
                hs_ptr[s * hs_stride] = (_Float16)hq[s];
            hs_ptr += hs_delta;
        } else {
            if (t == T - 1) {
                #pragma unroll
                for (int s = 0; s < 2; s++)
                    hlast[(bbase + rowbase + s) * (2 * U) + dir * U + ucol] = hq[s];
            }
        }
    };

    // PF-deep prologue prefetch (rotating register buffers, static indices)
    half8 xq[PF][XT];
    #pragma unroll
    for (int i = 0; i < PF; i++) load_x(xq[i]);
    __syncthreads();                          // H zero-init visible (once)

    // main groups refill; final PF steps don't (their data already resident)
    for (int g = 0; g < T / PF - 1; g++) {
        #pragma unroll
        for (int i = 0; i < PF; i++)
            step(g * PF + i, xq[i], true);
    }
    #pragma unroll
    for (int i = 0; i < PF; i++)
        step(T - PF + i, xq[i], false);
}

__global__ __launch_bounds__(256)
void dense_head(const float* __restrict__ h3,
                const float* __restrict__ w1, const float* __restrict__ b1,
                const float* __restrict__ w2, const float* __restrict__ b2,
                float* __restrict__ out)
{
    const int r = blockIdx.x * 256 + threadIdx.x;
    if (r >= 1024) return;
    float h[32];
    #pragma unroll
    for (int k = 0; k < 32; k++) h[k] = h3[r * 32 + k];
    float d1[8];
    #pragma unroll
    for (int j = 0; j < 8; j++) {
        float a = b1[j];
        #pragma unroll
        for (int k = 0; k < 32; k++) a += h[k] * w1[k * 8 + j];
        d1[j] = fmaxf(a, 0.0f);
    }
    #pragma unroll
    for (int c = 0; c < 3; c++) {
        float s = b2[c];
        #pragma unroll
        for (int j = 0; j < 8; j++) s += d1[j] * w2[j * 3 + c];
        out[r * 3 + c] = 1.0f / (1.0f + __expf(-s));
    }
}

extern "C" void kernel_launch(void* const* d_in, const int* in_sizes, int n_in,
                              void* d_out, int out_size, void* d_ws, size_t ws_size,
                              hipStream_t stream)
{
    const float* x     = (const float*)d_in[0];
    const float* w1f_k = (const float*)d_in[1];
    const float* w1f_r = (const float*)d_in[2];
    const float* w1f_b = (const float*)d_in[3];
    const float* w1b_k = (const float*)d_in[4];
    const float* w1b_r = (const float*)d_in[5];
    const float* w1b_b = (const float*)d_in[6];
    const float* w2f_k = (const float*)d_in[7];
    const float* w2f_r = (const float*)d_in[8];
    const float* w2f_b = (const float*)d_in[9];
    const float* w2b_k = (const float*)d_in[10];
    const float* w2b_r = (const float*)d_in[11];
    const float* w2b_b = (const float*)d_in[12];
    const float* w3f_k = (const float*)d_in[13];
    const float* w3f_r = (const float*)d_in[14];
    const float* w3f_b = (const float*)d_in[15];
    const float* w3b_k = (const float*)d_in[16];
    const float* w3b_r = (const float*)d_in[17];
    const float* w3b_b = (const float*)d_in[18];
    const float* d3_w  = (const float*)d_in[19];
    const float* d3_b  = (const float*)d_in[20];
    const float* cls_w = (const float*)d_in[21];
    const float* cls_b = (const float*)d_in[22];

    char* ws = (char*)d_ws;
    _Float16* h1  = (_Float16*)(ws + 4096);          // 33.5 MB [1024][128][128]
    _Float16* h2  = (_Float16*)(ws + 4096 + 33554432);   // 16.8 MB [1024][128][64]
    float*    h3  = (float*)   (ws + 4096 + 50331648);   // 131 KB  [1024][32]
    half8*    wf  = (half8*)   (ws + 4096 + 50462720);   // 176 KB packed Wk frags
    float4*   bf4 = (float4*)  (ws + 4096 + 50642944);   // 14 KB scaled biases

    prep<<<dim3(4), dim3(256), 0, stream>>>(
        w1f_k, w1f_b, w1b_k, w1b_b, w2f_k, w2f_b, w2b_k, w2b_b,
        w3f_k, w3f_b, w3b_k, w3b_b, wf, bf4);

    // L1: direct f32 x (IN_F=78), XT=3 (k padded to 96 via masks), U=64, PF=4
    lstm_rec_fused<64, 3, 2, true, 78, 4, true><<<dim3(256), dim3(256), 0, stream>>>(
        x, wf, bf4, w1f_r, w1b_r, h1, nullptr);

    // L2: IN_F=128 f16, XT=4, U=32, PF=4
    lstm_rec_fused<32, 4, 1, true, 128, 4, false><<<dim3(256), dim3(128), 0, stream>>>(
        h1, wf + 6144, bf4 + 512, w2f_r, w2b_r, h2, nullptr);

    // L3: IN_F=64 f16, XT=2, U=16, PF=8
    lstm_rec_fused<16, 2, 1, false, 64, 8, false><<<dim3(256), dim3(64), 0, stream>>>(
        h2, wf + 10240, bf4 + 768, w3f_r, w3b_r, nullptr, h3);

    dense_head<<<dim3(4), dim3(256), 0, stream>>>(h3, d3_w, d3_b, cls_w, cls_b, (float*)d_out);
}

// Round 10
// 295.500 us; speedup vs baseline: 1.3761x; 1.3761x over previous
//
#include <hip/hip_runtime.h>

typedef _Float16 half8 __attribute__((ext_vector_type(8)));
typedef float floatx4 __attribute__((ext_vector_type(4)));

__device__ __forceinline__ float rcpf_(float x) { return __builtin_amdgcn_rcpf(x); }
__device__ __forceinline__ float exp2f_(float x) { return __builtin_amdgcn_exp2f(x); }

// Barrier that does NOT drain vmem: only LDS ops published.
// 0xC07F = vmcnt(63) expcnt(7) lgkmcnt(0).
template<bool MULTI_WAVE>
__device__ __forceinline__ void lds_publish_barrier() {
    asm volatile("" ::: "memory");
    __builtin_amdgcn_s_waitcnt(0xC07F);
    if constexpr (MULTI_WAVE) __builtin_amdgcn_s_barrier();
    asm volatile("" ::: "memory");
}

struct AllParams {
    const float *x;
    const float *w1f_k, *w1f_b, *w1b_k, *w1b_b;
    const float *w2f_k, *w2f_b, *w2b_k, *w2b_b;
    const float *w3f_k, *w3f_b, *w3b_k, *w3b_b;
    _Float16 *x16;
    half8 *wf; float4 *bf4;
};

// ---------- pack Wk weights + bias into per-(dir,wave,lane) MFMA B-fragments.
// exp2-folding: gates i,f,o scaled by log2e; gate g (tanh) by 2*log2e.
template<int F_REAL, int XT, int U>
__device__ __forceinline__ void pack_one(int dir, int wave, int lane,
    const float* Wk_f, const float* b_f, const float* Wk_b, const float* b_b,
    half8* wf, float4* bf4)
{
    constexpr int N  = 4 * U;
    constexpr int NW = U / 16;
    const int quad = lane >> 4, l16 = lane & 15;
    const float* Wk = dir ? Wk_b : Wk_f;
    const float* bs = dir ? b_b  : b_f;
    const int ucol = wave * 16 + l16;
    const long base = ((long)(dir * NW + wave) * 64 + lane) * (4 * XT);
    #pragma unroll
    for (int g = 0; g < 4; g++) {
        const float sc = (g == 2) ? 2.88539008177793f : 1.44269504088896f;
        const int n = g * U + ucol;
        #pragma unroll
        for (int kt = 0; kt < XT; kt++) {
            half8 h;
            #pragma unroll
            for (int j = 0; j < 8; j++) {
                const int k = kt * 32 + quad * 8 + j;
                h[j] = (k < F_REAL) ? (_Float16)(Wk[k * N + n] * sc) : (_Float16)0;
            }
            wf[base + g * XT + kt] = h;
        }
    }
    float4 b;
    b.x = bs[0 * U + ucol] * 1.44269504088896f;
    b.y = bs[1 * U + ucol] * 1.44269504088896f;
    b.z = bs[2 * U + ucol] * 2.88539008177793f;
    b.w = bs[3 * U + ucol] * 1.44269504088896f;
    bf4[(dir * NW + wave) * 64 + lane] = b;
}

// ---------- prep: pack all layers + coalesced x->f16 (78 padded to 96).
// Output-linear mapping: 8 contiguous f16 per lane -> perfect 16B store
// coalescing; input read as aligned float2 pairs (78 even, col even).
// NOTE (R9 lesson): this ONE-PASS streaming conversion is strictly better
// than inline f32 loads in the recurrence (which re-read 8B-masked scattered
// pairs every step: L1 68.9 -> 188.4 us). Centralize format conversions.
__global__ __launch_bounds__(256)
void prep(AllParams p)
{
    const int gid = blockIdx.x * 256 + threadIdx.x;    // 1572864 threads
    if (gid < 512) {
        pack_one<78, 3, 64>(gid >> 8, (gid >> 6) & 3, gid & 63,
                            p.w1f_k, p.w1f_b, p.w1b_k, p.w1b_b, p.wf, p.bf4);
    } else if (gid < 768) {
        const int t2 = gid - 512;
        pack_one<128, 4, 32>(t2 >> 7, (t2 >> 6) & 1, t2 & 63,
                             p.w2f_k, p.w2f_b, p.w2b_k, p.w2b_b, p.wf + 6144, p.bf4 + 512);
    } else if (gid < 896) {
        const int t3 = gid - 768;
        pack_one<64, 2, 16>(t3 >> 6, 0, t3 & 63,
                            p.w3f_k, p.w3f_b, p.w3b_k, p.w3b_b, p.wf + 10240, p.bf4 + 768);
    }

    // x -> f16: element block e = gid*8 (col never crosses a 96-row: 8 | 96)
    const int e   = gid * 8;                           // < 12582912
    const int r   = e / 96;
    const int col = e - r * 96;
    half8 h = {};
    if (col < 78) {
        const float* ip = p.x + (long)r * 78 + col;
        const int n = (col == 72) ? 6 : 8;             // cols 78,79 -> pad 0
        #pragma unroll
        for (int j = 0; j < 8; j += 2) {
            if (j < n) {
                const float2 v = *(const float2*)(ip + j);
                h[j] = (_Float16)v.x; h[j + 1] = (_Float16)v.y;
            }
        }
    }
    *(half8*)(p.x16 + e) = h;
}

// ---------- fused recurrence: z = in@Wk (MFMA, pre-barrier, latency hidden)
// then += h@Wr (post-barrier), exp2 gates, bias as MFMA C-init, PF-deep
// register prefetch (rotating xq, static indices). A rows 8..15 duplicate
// rows 0..7 (ds_read broadcast) -> NO shuffles.
template<int U, int XT, int HT, bool SEQ_OUT, int IN_F, int PF>
__global__ __launch_bounds__(64 * (U / 16))
void lstm_rec_fused(const _Float16* __restrict__ in,   // [row][T][IN_F] f16
                    const half8* __restrict__ wf, const float4* __restrict__ bf4,
                    const float* __restrict__ Wr_f, const float* __restrict__ Wr_b,
                    _Float16* __restrict__ hseq, float* __restrict__ hlast)
{
    constexpr int T    = 128;
    constexpr int N    = 4 * U;
    constexpr int NW   = U / 16;
    constexpr int HROW = HT * 32 + 8;        // f16/row, 16B-aligned stride
    constexpr int THREADS = NW * 64;
    static_assert(T % PF == 0, "PF must divide T");

    const int tid  = threadIdx.x;
    const int wave = tid >> 6;
    const int lane = tid & 63;
    const int quad = lane >> 4;
    const int l16  = lane & 15;

    const int dir   = blockIdx.x >> 7;
    const int bg    = blockIdx.x & 127;
    const int bbase = bg * 8;
    const int ucol  = wave * 16 + l16;

    const float* Wr = dir ? Wr_b : Wr_f;

    __shared__ __align__(16) _Float16 H[2][8][HROW];
    for (int i = tid; i < 2 * 8 * HROW; i += THREADS)
        (&H[0][0][0])[i] = (_Float16)0;      // h0=0; pad and k>=U stay 0

    // packed Wk fragments (contiguous vector loads) + scaled bias
    const long wbase = ((long)(dir * NW + wave) * 64 + lane) * (4 * XT);
    half8 wk[4][XT];
    #pragma unroll
    for (int g = 0; g < 4; g++)
        #pragma unroll
        for (int kt = 0; kt < XT; kt++)
            wk[g][kt] = wf[wbase + g * XT + kt];
    const float4 b4 = bf4[(dir * NW + wave) * 64 + lane];
    // bias as MFMA C-init vectors (built once; removes 8 serial adds/step)
    floatx4 biasv[4];
    {
        const float bb[4] = {b4.x, b4.y, b4.z, b4.w};
        #pragma unroll
        for (int g = 0; g < 4; g++) {
            floatx4 v = {bb[g], bb[g], bb[g], bb[g]};
            biasv[g] = v;
        }
    }

    // Wr fragments, exp2-scaled at build
    half8 br[4][HT];
    #pragma unroll
    for (int g = 0; g < 4; g++) {
        const float sc = (g == 2) ? 2.88539008177793f : 1.44269504088896f;
        const int n = g * U + ucol;
        #pragma unroll
        for (int ht = 0; ht < HT; ht++) {
            half8 h;
            #pragma unroll
            for (int j = 0; j < 8; j++) {
                const int k = ht * 32 + quad * 8 + j;
                h[j] = (k < U) ? (_Float16)(Wr[k * N + n] * sc) : (_Float16)0;
            }
            br[g][ht] = h;
        }
    }

    // running per-lane input pointer (no clamp; <=PF-row overshoot lands in
    // workspace slack: 4KB headroom before x16, inter-buffer slack elsewhere)
    const int arow = bbase + (l16 & 7);
    const _Float16* xp = in + (long)arow * T * IN_F + quad * 8
                       + (dir ? (long)(T - 1) * IN_F : 0);
    const long xd = dir ? -(long)IN_F : (long)IN_F;
    auto load_x = [&](half8* xr) {
        #pragma unroll
        for (int kt = 0; kt < XT; kt++)
            xr[kt] = *(const half8*)(xp + kt * 32);
        xp += xd;
    };

    // quad -> 2 chains: q0:{0,1} q1:{4,5} q2:{2,3} q3:{6,7}
    const int rowbase = (quad & 1) * 4 + (quad >> 1) * 2;
    const bool hi_rows = (quad & 2) != 0;
    float c_reg[2] = {0.0f, 0.0f};

    const int tp0 = dir ? (T - 1) : 0;
    const long hs_stride = (long)T * (2 * U);
    _Float16* hs_ptr = SEQ_OUT
        ? hseq + ((long)(bbase + rowbase) * T + tp0) * (2 * U) + dir * U + ucol
        : nullptr;
    const long hs_delta = dir ? -(long)(2 * U) : (long)(2 * U);

    auto step = [&](int t, half8* xr) {
        // z-part: independent of H -> issued before barrier, latency hidden
        floatx4 acc[4];
        #pragma unroll
        for (int g = 0; g < 4; g++)
            acc[g] = __builtin_amdgcn_mfma_f32_16x16x32_f16(xr[0], wk[g][0], biasv[g], 0, 0, 0);
        #pragma unroll
        for (int kt = 1; kt < XT; kt++)
            #pragma unroll
            for (int g = 0; g < 4; g++)
                acc[g] = __builtin_amdgcn_mfma_f32_16x16x32_f16(xr[kt], wk[g][kt], acc[g], 0, 0, 0);
        load_x(xr);                    // refill slot (reads t+PF); stays in flight
        lds_publish_barrier<(NW > 1)>();
        const _Float16* hb = &H[t & 1][l16 & 7][0];   // rows 8..15 = dup of 0..7
        #pragma unroll
        for (int ht = 0; ht < HT; ht++) {
            const half8 ha = *(const half8*)(hb + ht * 32 + quad * 8);
            #pragma unroll
            for (int g = 0; g < 4; g++)
                acc[g] = __builtin_amdgcn_mfma_f32_16x16x32_f16(ha, br[g][ht], acc[g], 0, 0, 0);
        }
        float hq[2];
        #pragma unroll
        for (int s = 0; s < 2; s++) {
            const int r = hi_rows ? (2 + s) : s;
            const float yi = acc[0][r];             // bias pre-added via C-init
            const float yf = acc[1][r];
            const float yg = acc[2][r];
            const float yo = acc[3][r];
            const float ig = rcpf_(1.0f + exp2f_(-yi));
            const float fg = rcpf_(1.0f + exp2f_(-yf));
            const float gg = 1.0f - 2.0f * rcpf_(exp2f_(yg) + 1.0f);
            const float og = rcpf_(1.0f + exp2f_(-yo));
            const float c  = fg * c_reg[s] + ig * gg;
            c_reg[s] = c;
            const float th = 1.0f - 2.0f * rcpf_(exp2f_(c * 2.88539008177793f) + 1.0f);
            hq[s] = og * th;
        }
        #pragma unroll
        for (int s = 0; s < 2; s++)
            H[(t + 1) & 1][rowbase + s][ucol] = (_Float16)hq[s];
        if constexpr (SEQ_OUT) {
            #pragma unroll
            for (int s = 0; s < 2; s++)
                hs_ptr[s * hs_stride] = (_Float16)hq[s];
            hs_ptr += hs_delta;
        } else {
            if (t == T - 1) {
                #pragma unroll
                for (int s = 0; s < 2; s++)
                    hlast[(bbase + rowbase + s) * (2 * U) + dir * U + ucol] = hq[s];
            }
        }
    };

    // PF-deep prologue prefetch (rotating register buffers, static indices)
    half8 xq[PF][XT];
    #pragma unroll
    for (int i = 0; i < PF; i++) load_x(xq[i]);
    __syncthreads();                          // H zero-init visible (once)

    for (int tt = 0; tt < T; tt += PF) {
        #pragma unroll
        for (int i = 0; i < PF; i++)
            step(tt + i, xq[i]);
    }
}

__global__ __launch_bounds__(256)
void dense_head(const float* __restrict__ h3,
                const float* __restrict__ w1, const float* __restrict__ b1,
                const float* __restrict__ w2, const float* __restrict__ b2,
                float* __restrict__ out)
{
    const int r = blockIdx.x * 256 + threadIdx.x;
    if (r >= 1024) return;
    float h[32];
    #pragma unroll
    for (int k = 0; k < 32; k++) h[k] = h3[r * 32 + k];
    float d1[8];
    #pragma unroll
    for (int j = 0; j < 8; j++) {
        float a = b1[j];
        #pragma unroll
        for (int k = 0; k < 32; k++) a += h[k] * w1[k * 8 + j];
        d1[j] = fmaxf(a, 0.0f);
    }
    #pragma unroll
    for (int c = 0; c < 3; c++) {
        float s = b2[c];
        #pragma unroll
        for (int j = 0; j < 8; j++) s += d1[j] * w2[j * 3 + c];
        out[r * 3 + c] = 1.0f / (1.0f + __expf(-s));
    }
}

extern "C" void kernel_launch(void* const* d_in, const int* in_sizes, int n_in,
                              void* d_out, int out_size, void* d_ws, size_t ws_size,
                              hipStream_t stream)
{
    const float* x     = (const float*)d_in[0];
    const float* w1f_k = (const float*)d_in[1];
    const float* w1f_r = (const float*)d_in[2];
    const float* w1f_b = (const float*)d_in[3];
    const float* w1b_k = (const float*)d_in[4];
    const float* w1b_r = (const float*)d_in[5];
    const float* w1b_b = (const float*)d_in[6];
    const float* w2f_k = (const float*)d_in[7];
    const float* w2f_r = (const float*)d_in[8];
    const float* w2f_b = (const float*)d_in[9];
    const float* w2b_k = (const float*)d_in[10];
    const float* w2b_r = (const float*)d_in[11];
    const float* w2b_b = (const float*)d_in[12];
    const float* w3f_k = (const float*)d_in[13];
    const float* w3f_r = (const float*)d_in[14];
    const float* w3f_b = (const float*)d_in[15];
    const float* w3b_k = (const float*)d_in[16];
    const float* w3b_r = (const float*)d_in[17];
    const float* w3b_b = (const float*)d_in[18];
    const float* d3_w  = (const float*)d_in[19];
    const float* d3_b  = (const float*)d_in[20];
    const float* cls_w = (const float*)d_in[21];
    const float* cls_b = (const float*)d_in[22];

    char* ws = (char*)d_ws;
    AllParams p;
    p.x = x;
    p.w1f_k = w1f_k; p.w1f_b = w1f_b; p.w1b_k = w1b_k; p.w1b_b = w1b_b;
    p.w2f_k = w2f_k; p.w2f_b = w2f_b; p.w2b_k = w2b_k; p.w2b_b = w2b_b;
    p.w3f_k = w3f_k; p.w3f_b = w3f_b; p.w3b_k = w3b_k; p.w3b_b = w3b_b;

    // workspace (4KB headroom before x16 for bwd-dir prefetch overshoot)
    _Float16* x16 = (_Float16*)(ws + 4096);          // 25.2 MB [131072][96]
    _Float16* h1  = (_Float16*)(ws + 33554432);      // 33.5 MB [1024][128][128]
    _Float16* h2  = (_Float16*)(ws + 67108864);      // 16.8 MB [1024][128][64]
    float*    h3  = (float*)   (ws + 83886080);      // 131 KB  [1024][32]
    half8*    wf  = (half8*)   (ws + 84017152);      // 176 KB packed Wk frags
    float4*   bf4 = (float4*)  (ws + 84197376);      // 14 KB scaled biases
    p.x16 = x16; p.wf = wf; p.bf4 = bf4;

    prep<<<dim3(6144), dim3(256), 0, stream>>>(p);

    // L1: IN_F=96 (padded 78), XT=3, U=64, HT=2, PF=4
    lstm_rec_fused<64, 3, 2, true, 96, 4><<<dim3(256), dim3(256), 0, stream>>>(
        x16, wf, bf4, w1f_r, w1b_r, h1, nullptr);

    // L2: IN_F=128, XT=4, U=32, HT=1, PF=4
    lstm_rec_fused<32, 4, 1, true, 128, 4><<<dim3(256), dim3(128), 0, stream>>>(
        h1, wf + 6144, bf4 + 512, w2f_r, w2b_r, h2, nullptr);

    // L3: IN_F=64, XT=2, U=16, HT=1, PF=8 (short step -> deepest lookahead)
    lstm_rec_fused<16, 2, 1, false, 64, 8><<<dim3(256), dim3(64), 0, stream>>>(
        h2, wf + 10240, bf4 + 768, w3f_r, w3b_r, nullptr, h3);

    dense_head<<<dim3(4), dim3(256), 0, stream>>>(h3, d3_w, d3_b, cls_w, cls_b, (float*)d_out);
}

// Round 11
// 290.903 us; speedup vs baseline: 1.3979x; 1.0158x over previous
//
#include <hip/hip_runtime.h>

typedef _Float16 half8 __attribute__((ext_vector_type(8)));
typedef float floatx4 __attribute__((ext_vector_type(4)));

__device__ __forceinline__ float rcpf_(float x) { return __builtin_amdgcn_rcpf(x); }
__device__ __forceinline__ float exp2f_(float x) { return __builtin_amdgcn_exp2f(x); }

// Barrier that does NOT drain vmem: only LDS ops published.
// 0xC07F = vmcnt(63) expcnt(7) lgkmcnt(0).
template<bool MULTI_WAVE>
__device__ __forceinline__ void lds_publish_barrier() {
    asm volatile("" ::: "memory");
    __builtin_amdgcn_s_waitcnt(0xC07F);
    if constexpr (MULTI_WAVE) __builtin_amdgcn_s_barrier();
    asm volatile("" ::: "memory");
}

struct AllParams {
    const float *x;
    const float *w1f_k, *w1f_b, *w1b_k, *w1b_b;
    const float *w2f_k, *w2f_b, *w2b_k, *w2b_b;
    const float *w3f_k, *w3f_b, *w3b_k, *w3b_b;
    _Float16 *x16;
    half8 *wf; float4 *bf4;
};

// ---------- pack Wk weights + bias into per-(dir,wave,lane) MFMA B-fragments.
// exp2-folding: gates i,f,o scaled by log2e; gate g (tanh) by 2*log2e.
template<int F_REAL, int XT, int U>
__device__ __forceinline__ void pack_one(int dir, int wave, int lane,
    const float* Wk_f, const float* b_f, const float* Wk_b, const float* b_b,
    half8* wf, float4* bf4)
{
    constexpr int N  = 4 * U;
    constexpr int NW = U / 16;
    const int quad = lane >> 4, l16 = lane & 15;
    const float* Wk = dir ? Wk_b : Wk_f;
    const float* bs = dir ? b_b  : b_f;
    const int ucol = wave * 16 + l16;
    const long base = ((long)(dir * NW + wave) * 64 + lane) * (4 * XT);
    #pragma unroll
    for (int g = 0; g < 4; g++) {
        const float sc = (g == 2) ? 2.88539008177793f : 1.44269504088896f;
        const int n = g * U + ucol;
        #pragma unroll
        for (int kt = 0; kt < XT; kt++) {
            half8 h;
            #pragma unroll
            for (int j = 0; j < 8; j++) {
                const int k = kt * 32 + quad * 8 + j;
                h[j] = (k < F_REAL) ? (_Float16)(Wk[k * N + n] * sc) : (_Float16)0;
            }
            wf[base + g * XT + kt] = h;
        }
    }
    float4 b;
    b.x = bs[0 * U + ucol] * 1.44269504088896f;
    b.y = bs[1 * U + ucol] * 1.44269504088896f;
    b.z = bs[2 * U + ucol] * 2.88539008177793f;
    b.w = bs[3 * U + ucol] * 1.44269504088896f;
    bf4[(dir * NW + wave) * 64 + lane] = b;
}

// ---------- prep: pack all layers + coalesced x->f16 (78 padded to 96).
// NOTE (R9 lesson): one-pass streaming conversion beats inline f32 loads in
// the recurrence (68.9 -> 188.4 us when distributed). Centralize conversions.
__global__ __launch_bounds__(256)
void prep(AllParams p)
{
    const int gid = blockIdx.x * 256 + threadIdx.x;    // 1572864 threads
    if (gid < 512) {
        pack_one<78, 3, 64>(gid >> 8, (gid >> 6) & 3, gid & 63,
                            p.w1f_k, p.w1f_b, p.w1b_k, p.w1b_b, p.wf, p.bf4);
    } else if (gid < 768) {
        const int t2 = gid - 512;
        pack_one<128, 4, 32>(t2 >> 7, (t2 >> 6) & 1, t2 & 63,
                             p.w2f_k, p.w2f_b, p.w2b_k, p.w2b_b, p.wf + 6144, p.bf4 + 512);
    } else if (gid < 896) {
        const int t3 = gid - 768;
        pack_one<64, 2, 16>(t3 >> 6, 0, t3 & 63,
                            p.w3f_k, p.w3f_b, p.w3b_k, p.w3b_b, p.wf + 10240, p.bf4 + 768);
    }

    // x -> f16: element block e = gid*8 (col never crosses a 96-row: 8 | 96)
    const int e   = gid * 8;                           // < 12582912
    const int r   = e / 96;
    const int col = e - r * 96;
    half8 h = {};
    if (col < 78) {
        const float* ip = p.x + (long)r * 78 + col;
        const int n = (col == 72) ? 6 : 8;             // cols 78,79 -> pad 0
        #pragma unroll
        for (int j = 0; j < 8; j += 2) {
            if (j < n) {
                const float2 v = *(const float2*)(ip + j);
                h[j] = (_Float16)v.x; h[j + 1] = (_Float16)v.y;
            }
        }
    }
    *(half8*)(p.x16 + e) = h;
}

// ---------- fused recurrence, cross-barrier software-pipelined z-phase (R11).
// Step layout (vs R5/R10): z tiles split A|B around the barrier so both LDS
// round-trip stalls are covered by H-independent MFMA issue:
//   [barrier] -> ds_read H[t] -> z-partB(t)   (covers ~120cy read latency)
//   -> h-MFMA -> gates -> ds_write H[t+1]
//   -> z-partA(t+1) into accP                 (covers ~120cy write drain)
//   -> lgkmcnt(0); s_barrier
// Same MFMA count / rounding / traffic as R10 -- pure issue reordering.
// A rows 8..15 duplicate rows 0..7 (ds_read broadcast) -> NO shuffles.
template<int U, int XT, int HT, bool SEQ_OUT, int IN_F, int PF>
__global__ __launch_bounds__(64 * (U / 16))
void lstm_rec_fused(const _Float16* __restrict__ in,   // [row][T][IN_F] f16
                    const half8* __restrict__ wf, const float4* __restrict__ bf4,
                    const float* __restrict__ Wr_f, const float* __restrict__ Wr_b,
                    _Float16* __restrict__ hseq, float* __restrict__ hlast)
{
    constexpr int T    = 128;
    constexpr int N    = 4 * U;
    constexpr int NW   = U / 16;
    constexpr int HROW = HT * 32 + 8;        // f16/row, 16B-aligned stride
    constexpr int THREADS = NW * 64;
    constexpr int AXT  = ((2 * XT) / 3) < 1 ? 1 : ((2 * XT) / 3);  // pre-barrier tiles
    static_assert(T % PF == 0, "PF must divide T");
    static_assert(PF >= 2, "PF>=2 so xq[t+1] slot is resident for partA");
    static_assert(AXT >= 1 && AXT < XT, "need tiles on both barrier sides");

    const int tid  = threadIdx.x;
    const int wave = tid >> 6;
    const int lane = tid & 63;
    const int quad = lane >> 4;
    const int l16  = lane & 15;

    const int dir   = blockIdx.x >> 7;
    const int bg    = blockIdx.x & 127;
    const int bbase = bg * 8;
    const int ucol  = wave * 16 + l16;

    const float* Wr = dir ? Wr_b : Wr_f;

    __shared__ __align__(16) _Float16 H[2][8][HROW];
    for (int i = tid; i < 2 * 8 * HROW; i += THREADS)
        (&H[0][0][0])[i] = (_Float16)0;      // h0=0; pad and k>=U stay 0

    // packed Wk fragments (contiguous vector loads) + scaled bias
    const long wbase = ((long)(dir * NW + wave) * 64 + lane) * (4 * XT);
    half8 wk[4][XT];
    #pragma unroll
    for (int g = 0; g < 4; g++)
        #pragma unroll
        for (int kt = 0; kt < XT; kt++)
            wk[g][kt] = wf[wbase + g * XT + kt];
    const float4 b4 = bf4[(dir * NW + wave) * 64 + lane];
    // bias as MFMA C-init vectors (built once; removes 8 serial adds/step)
    floatx4 biasv[4];
    {
        const float bb[4] = {b4.x, b4.y, b4.z, b4.w};
        #pragma unroll
        for (int g = 0; g < 4; g++) {
            floatx4 v = {bb[g], bb[g], bb[g], bb[g]};
            biasv[g] = v;
        }
    }

    // Wr fragments, exp2-scaled at build
    half8 br[4][HT];
    #pragma unroll
    for (int g = 0; g < 4; g++) {
        const float sc = (g == 2) ? 2.88539008177793f : 1.44269504088896f;
        const int n = g * U + ucol;
        #pragma unroll
        for (int ht = 0; ht < HT; ht++) {
            half8 h;
            #pragma unroll
            for (int j = 0; j < 8; j++) {
                const int k = ht * 32 + quad * 8 + j;
                h[j] = (k < U) ? (_Float16)(Wr[k * N + n] * sc) : (_Float16)0;
            }
            br[g][ht] = h;
        }
    }

    // running per-lane input pointer (no clamp; <=PF-row overshoot lands in
    // workspace slack: 4KB headroom before x16, inter-buffer slack elsewhere)
    const int arow = bbase + (l16 & 7);
    const _Float16* xp = in + (long)arow * T * IN_F + quad * 8
                       + (dir ? (long)(T - 1) * IN_F : 0);
    const long xd = dir ? -(long)IN_F : (long)IN_F;
    auto load_x = [&](half8* xr) {
        #pragma unroll
        for (int kt = 0; kt < XT; kt++)
            xr[kt] = *(const half8*)(xp + kt * 32);
        xp += xd;
    };

    // quad -> 2 chains: q0:{0,1} q1:{4,5} q2:{2,3} q3:{6,7}
    const int rowbase = (quad & 1) * 4 + (quad >> 1) * 2;
    const bool hi_rows = (quad & 2) != 0;
    float c_reg[2] = {0.0f, 0.0f};

    const int tp0 = dir ? (T - 1) : 0;
    const long hs_stride = (long)T * (2 * U);
    _Float16* hs_ptr = SEQ_OUT
        ? hseq + ((long)(bbase + rowbase) * T + tp0) * (2 * U) + dir * U + ucol
        : nullptr;
    const long hs_delta = dir ? -(long)(2 * U) : (long)(2 * U);

    // z-partA: tiles 0..AXT-1 (bias C-init), H-independent -> issued
    // pre-barrier to cover the ds_write drain of the current step.
    floatx4 accP[4];
    auto zpartA = [&](const half8* xr) {
        #pragma unroll
        for (int g = 0; g < 4; g++)
            accP[g] = __builtin_amdgcn_mfma_f32_16x16x32_f16(xr[0], wk[g][0], biasv[g], 0, 0, 0);
        #pragma unroll
        for (int kt = 1; kt < AXT; kt++)
            #pragma unroll
            for (int g = 0; g < 4; g++)
                accP[g] = __builtin_amdgcn_mfma_f32_16x16x32_f16(xr[kt], wk[g][kt], accP[g], 0, 0, 0);
    };

    auto step = [&](int t, half8* xr, const half8* xrn) {
        // ---- post-barrier: issue H reads first; z-partB hides their latency
        half8 ha[HT];
        const _Float16* hb = &H[t & 1][l16 & 7][0];   // rows 8..15 = dup of 0..7
        #pragma unroll
        for (int ht = 0; ht < HT; ht++)
            ha[ht] = *(const half8*)(hb + ht * 32 + quad * 8);
        floatx4 acc[4];
        #pragma unroll
        for (int g = 0; g < 4; g++) acc[g] = accP[g];
        #pragma unroll
        for (int kt = AXT; kt < XT; kt++)
            #pragma unroll
            for (int g = 0; g < 4; g++)
                acc[g] = __builtin_amdgcn_mfma_f32_16x16x32_f16(xr[kt], wk[g][kt], acc[g], 0, 0, 0);
        load_x(xr);                    // refill slot t%PF (row t+PF); in flight
        #pragma unroll
        for (int ht = 0; ht < HT; ht++) {
            #pragma unroll
            for (int g = 0; g < 4; g++)
                acc[g] = __builtin_amdgcn_mfma_f32_16x16x32_f16(ha[ht], br[g][ht], acc[g], 0, 0, 0);
        }
        float hq[2];
        #pragma unroll
        for (int s = 0; s < 2; s++) {
            const int r = hi_rows ? (2 + s) : s;
            const float ig = rcpf_(1.0f + exp2f_(-acc[0][r]));
            const float fg = rcpf_(1.0f + exp2f_(-acc[1][r]));
            const float gg = 1.0f - 2.0f * rcpf_(exp2f_(acc[2][r]) + 1.0f);
            const float og = rcpf_(1.0f + exp2f_(-acc[3][r]));
            const float c  = fg * c_reg[s] + ig * gg;
            c_reg[s] = c;
            const float th = 1.0f - 2.0f * rcpf_(exp2f_(c * 2.88539008177793f) + 1.0f);
            hq[s] = og * th;
        }
        #pragma unroll
        for (int s = 0; s < 2; s++)
            H[(t + 1) & 1][rowbase + s][ucol] = (_Float16)hq[s];
        if constexpr (SEQ_OUT) {
            #pragma unroll
            for (int s = 0; s < 2; s++)
                hs_ptr[s * hs_stride] = (_Float16)hq[s];
            hs_ptr += hs_delta;
        } else {
            if (t == T - 1) {
                #pragma unroll
                for (int s = 0; s < 2; s++)
                    hlast[(bbase + rowbase + s) * (2 * U) + dir * U + ucol] = hq[s];
            }
        }
        // ---- pre-barrier: z-partA for t+1 covers the H write drain.
        // (at t==T-1 this computes a discarded tile from slack-valid data)
        zpartA(xrn);
        lds_publish_barrier<(NW > 1)>();
    };

    // PF-deep prologue prefetch (rotating register buffers, static indices)
    half8 xq[PF][XT];
    #pragma unroll
    for (int i = 0; i < PF; i++) load_x(xq[i]);
    zpartA(xq[0]);                            // partA(0)
    lds_publish_barrier<(NW > 1)>();          // H zero-init visible
    if constexpr (NW == 1) __syncthreads();   // (no-op safety for 1-wave blocks)

    for (int tt = 0; tt < T; tt += PF) {
        #pragma unroll
        for (int i = 0; i < PF; i++)
            step(tt + i, xq[i], xq[(i + 1) % PF]);
    }
}

__global__ __launch_bounds__(256)
void dense_head(const float* __restrict__ h3,
                const float* __restrict__ w1, const float* __restrict__ b1,
                const float* __restrict__ w2, const float* __restrict__ b2,
                float* __restrict__ out)
{
    const int r = blockIdx.x * 256 + threadIdx.x;
    if (r >= 1024) return;
    float h[32];
    #pragma unroll
    for (int k = 0; k < 32; k++) h[k] = h3[r * 32 + k];
    float d1[8];
    #pragma unroll
    for (int j = 0; j < 8; j++) {
        float a = b1[j];
        #pragma unroll
        for (int k = 0; k < 32; k++) a += h[k] * w1[k * 8 + j];
        d1[j] = fmaxf(a, 0.0f);
    }
    #pragma unroll
    for (int c = 0; c < 3; c++) {
        float s = b2[c];
        #pragma unroll
        for (int j = 0; j < 8; j++) s += d1[j] * w2[j * 3 + c];
        out[r * 3 + c] = 1.0f / (1.0f + __expf(-s));
    }
}

extern "C" void kernel_launch(void* const* d_in, const int* in_sizes, int n_in,
                              void* d_out, int out_size, void* d_ws, size_t ws_size,
                              hipStream_t stream)
{
    const float* x     = (const float*)d_in[0];
    const float* w1f_k = (const float*)d_in[1];
    const float* w1f_r = (const float*)d_in[2];
    const float* w1f_b = (const float*)d_in[3];
    const float* w1b_k = (const float*)d_in[4];
    const float* w1b_r = (const float*)d_in[5];
    const float* w1b_b = (const float*)d_in[6];
    const float* w2f_k = (const float*)d_in[7];
    const float* w2f_r = (const float*)d_in[8];
    const float* w2f_b = (const float*)d_in[9];
    const float* w2b_k = (const float*)d_in[10];
    const float* w2b_r = (const float*)d_in[11];
    const float* w2b_b = (const float*)d_in[12];
    const float* w3f_k = (const float*)d_in[13];
    const float* w3f_r = (const float*)d_in[14];
    const float* w3f_b = (const float*)d_in[15];
    const float* w3b_k = (const float*)d_in[16];
    const float* w3b_r = (const float*)d_in[17];
    const float* w3b_b = (const float*)d_in[18];
    const float* d3_w  = (const float*)d_in[19];
    const float* d3_b  = (const float*)d_in[20];
    const float* cls_w = (const float*)d_in[21];
    const float* cls_b = (const float*)d_in[22];

    char* ws = (char*)d_ws;
    AllParams p;
    p.x = x;
    p.w1f_k = w1f_k; p.w1f_b = w1f_b; p.w1b_k = w1b_k; p.w1b_b = w1b_b;
    p.w2f_k = w2f_k; p.w2f_b = w2f_b; p.w2b_k = w2b_k; p.w2b_b = w2b_b;
    p.w3f_k = w3f_k; p.w3f_b = w3f_b; p.w3b_k = w3b_k; p.w3b_b = w3b_b;

    // workspace (4KB headroom before x16 for bwd-dir prefetch overshoot)
    _Float16* x16 = (_Float16*)(ws + 4096);          // 25.2 MB [131072][96]
    _Float16* h1  = (_Float16*)(ws + 33554432);      // 33.5 MB [1024][128][128]
    _Float16* h2  = (_Float16*)(ws + 67108864);      // 16.8 MB [1024][128][64]
    float*    h3  = (float*)   (ws + 83886080);      // 131 KB  [1024][32]
    half8*    wf  = (half8*)   (ws + 84017152);      // 176 KB packed Wk frags
    float4*   bf4 = (float4*)  (ws + 84197376);      // 14 KB scaled biases
    p.x16 = x16; p.wf = wf; p.bf4 = bf4;

    prep<<<dim3(6144), dim3(256), 0, stream>>>(p);

    // L1: IN_F=96 (padded 78), XT=3 (A=2|B=1), U=64, HT=2, PF=4
    lstm_rec_fused<64, 3, 2, true, 96, 4><<<dim3(256), dim3(256), 0, stream>>>(
        x16, wf, bf4, w1f_r, w1b_r, h1, nullptr);

    // L2: IN_F=128, XT=4 (A=2|B=2), U=32, HT=1, PF=4
    lstm_rec_fused<32, 4, 1, true, 128, 4><<<dim3(256), dim3(128), 0, stream>>>(
        h1, wf + 6144, bf4 + 512, w2f_r, w2b_r, h2, nullptr);

    // L3: IN_F=64, XT=2 (A=1|B=1), U=16, HT=1, PF=8
    lstm_rec_fused<16, 2, 1, false, 64, 8><<<dim3(256), dim3(64), 0, stream>>>(
        h2, wf + 10240, bf4 + 768, w3f_r, w3b_r, nullptr, h3);

    dense_head<<<dim3(4), dim3(256), 0, stream>>>(h3, d3_w, d3_b, cls_w, cls_b, (float*)d_out);
}